// Round 14
// baseline (208.263 us; speedup 1.0000x reference)
//
#include <hip/hip_runtime.h>

typedef unsigned short u16;
typedef unsigned short u16x8 __attribute__((ext_vector_type(8)));
typedef unsigned short u16x4 __attribute__((ext_vector_type(4)));
typedef short s16x8 __attribute__((ext_vector_type(8)));
typedef float f32x4 __attribute__((ext_vector_type(4)));
typedef float f32x16 __attribute__((ext_vector_type(16)));
typedef unsigned u32x4 __attribute__((ext_vector_type(4)));

__device__ __forceinline__ u16 f2b(float f){
  unsigned u = __builtin_bit_cast(unsigned, f);
  u += 0x7fffu + ((u >> 16) & 1u);
  return (u16)(u >> 16);
}
__device__ __forceinline__ float b2f(u16 v){
  unsigned u = ((unsigned)v) << 16;
  return __builtin_bit_cast(float, u);
}

#define MFMA16(c, a, b) (c) = __builtin_amdgcn_mfma_f32_16x16x32_bf16((a), (b), (c), 0, 0, 0)
#define MFMA32(c, a, b) (c) = __builtin_amdgcn_mfma_f32_32x32x16_bf16((a), (b), (c), 0, 0, 0)

__device__ __forceinline__ void gl16(const u16* g, char* l){
  __builtin_amdgcn_global_load_lds((const __attribute__((address_space(1))) void*)g,
                                   (__attribute__((address_space(3))) void*)l, 16, 0, 0);
}

// ---------------- cast hidden_states f32 -> bf16 ----------------
__global__ void k_cast(const float* __restrict__ src, u16* __restrict__ dst, int n8){
  int i = blockIdx.x * blockDim.x + threadIdx.x;
  if (i >= n8) return;
  const float4* s = (const float4*)(src + (size_t)i * 8);
  float4 a = s[0], b = s[1];
  u16x8 o;
  o[0]=f2b(a.x); o[1]=f2b(a.y); o[2]=f2b(a.z); o[3]=f2b(a.w);
  o[4]=f2b(b.x); o[5]=f2b(b.y); o[6]=f2b(b.z); o[7]=f2b(b.w);
  *(u16x8*)(dst + (size_t)i * 8) = o;
}

// ------- all 4 weight transposes in ONE launch (region-decoded) -------
__global__ void k_transall(const float* __restrict__ Wq, const float* __restrict__ Wk,
                           const float* __restrict__ Wv, const float* __restrict__ Wo,
                           u16* __restrict__ wqkvT, u16* __restrict__ woT){
  __shared__ float t[32][33];
  int by = blockIdx.y;
  const float* src; u16* dst; int N;
  if (by < 64)       { src = Wq; dst = wqkvT;                        N = 2048; }
  else if (by < 128) { src = Wk; dst = wqkvT + (size_t)2048 * 2048;  N = 1024; by -= 64; }
  else if (by < 192) { src = Wv; dst = wqkvT + (size_t)3072 * 2048;  N = 1024; by -= 128; }
  else               { src = Wo; dst = woT;                          N = 2048; by -= 192; }
  int n0 = blockIdx.x * 32, k0 = by * 32;
  if (n0 >= N) return;
  int c = threadIdx.x & 31, r4 = threadIdx.x >> 5;
  #pragma unroll
  for (int p = 0; p < 4; ++p){
    int r = r4 + p * 8;
    t[r][c] = src[(size_t)(k0 + r) * N + n0 + c];
  }
  __syncthreads();
  #pragma unroll
  for (int p = 0; p < 4; ++p){
    int r = r4 + p * 8;
    dst[(size_t)(n0 + r) * 2048 + k0 + c] = f2b(t[c][r]);
  }
}

// ---------------- 8-phase GEMM: C = A(MxK) * BT(NxK)^T ----------------
template<int NREP, int MODE>
__global__ __launch_bounds__(512, 1) void k_gemm8(const u16* __restrict__ A, const u16* __restrict__ BT,
                                                  float* __restrict__ Cv, int M, int N, int K,
                                                  u16* __restrict__ qout, u16* __restrict__ kout,
                                                  u16* __restrict__ vout,
                                                  const float* __restrict__ cosT, const float* __restrict__ sinT,
                                                  const float* __restrict__ qw, const float* __restrict__ kw){
  constexpr int NH = NREP / 2;
  constexpr int BROWS = NREP * 32;
  constexpr int BLOADS = NREP / 2;
  constexpr int TOT = 4 + 2 * BLOADS;
  constexpr int SMEM0 = 65536 + 2 * 2 * BROWS * 64 * 2;
  constexpr int SMEM = (SMEM0 > 131072) ? SMEM0 : 131072;
  __shared__ __align__(128) char smem[SMEM];
  u16* sAp = (u16*)smem;
  u16* sBp = (u16*)(smem + 65536);
  const int tid = threadIdx.x;
  const int lane = tid & 63, w = tid >> 6;
  const int l15 = lane & 15, l4 = lane >> 4;
  const int sx = l15 & 7;
  const int wr = w >> 2, wc = w & 3;
  const int m0 = blockIdx.y * 256, n0 = blockIdx.x * (NREP * 64);
  const int nk = K >> 6;

  f32x4 acc[8][NREP];
  #pragma unroll
  for (int mi = 0; mi < 8; ++mi)
    #pragma unroll
    for (int ni = 0; ni < NREP; ++ni) acc[mi][ni] = (f32x4){0.f, 0.f, 0.f, 0.f};

  auto stageA = [&](int d, int half, int k0){
    #pragma unroll
    for (int j = 0; j < 2; ++j){
      const int q = j * 512 + tid;
      const int r = q >> 3, cc = q & 7;
      gl16(A + (size_t)(m0 + half * 128 + r) * K + k0 + ((cc ^ (r & 7)) << 3),
           (char*)(sAp + (d * 2 + half) * 8192) + j * 8192 + (tid >> 6) * 1024);
    }
  };
  auto stageB = [&](int d, int half, int k0){
    #pragma unroll
    for (int j = 0; j < BLOADS; ++j){
      const int q = j * 512 + tid;
      const int r = q >> 3, cc = q & 7;
      gl16(BT + (size_t)(n0 + half * BROWS + r) * K + k0 + ((cc ^ (r & 7)) << 3),
           (char*)(sBp + (d * 2 + half) * (BROWS * 64)) + j * 8192 + (tid >> 6) * 1024);
    }
  };

  stageA(0, 0, 0); stageA(0, 1, 0); stageB(0, 0, 0); stageB(0, 1, 0);
  stageA(1, 0, 64); stageA(1, 1, 64); stageB(1, 0, 64); stageB(1, 1, 64);
  if constexpr (TOT == 8) asm volatile("s_waitcnt vmcnt(8)" ::: "memory");
  else                    asm volatile("s_waitcnt vmcnt(6)" ::: "memory");
  __builtin_amdgcn_s_barrier();

  const int halfB = wc >> 1;
  const int rb0 = (wc & 1) * (NREP * 16);

  for (int kt = 0; kt < nk; ++kt){
    const int d = kt & 1;
    const bool pre = (kt + 2) < nk;
    const int k0n = (kt + 2) << 6;
    const char* hA = (const char*)(sAp + (d * 2 + wr) * 8192);
    const char* hB = (const char*)(sBp + (d * 2 + halfB) * (BROWS * 64));
    s16x8 aa[4][2], bb0[NH][2], bb1[NH][2];

    #pragma unroll
    for (int mi = 0; mi < 4; ++mi)
      #pragma unroll
      for (int kk = 0; kk < 2; ++kk)
        aa[mi][kk] = *(const s16x8*)(hA + (mi * 16 + l15) * 128 + (((kk * 4 + l4) ^ sx) << 4));
    #pragma unroll
    for (int ni = 0; ni < NH; ++ni)
      #pragma unroll
      for (int kk = 0; kk < 2; ++kk)
        bb0[ni][kk] = *(const s16x8*)(hB + (rb0 + ni * 16 + l15) * 128 + (((kk * 4 + l4) ^ sx) << 4));
    __builtin_amdgcn_s_setprio(1);
    #pragma unroll
    for (int mi = 0; mi < 4; ++mi)
      #pragma unroll
      for (int ni = 0; ni < NH; ++ni)
        #pragma unroll
        for (int kk = 0; kk < 2; ++kk)
          MFMA16(acc[mi][ni], aa[mi][kk], bb0[ni][kk]);
    __builtin_amdgcn_s_setprio(0);

    #pragma unroll
    for (int ni = 0; ni < NH; ++ni)
      #pragma unroll
      for (int kk = 0; kk < 2; ++kk)
        bb1[ni][kk] = *(const s16x8*)(hB + (rb0 + (NH + ni) * 16 + l15) * 128 + (((kk * 4 + l4) ^ sx) << 4));
    __builtin_amdgcn_s_setprio(1);
    #pragma unroll
    for (int mi = 0; mi < 4; ++mi)
      #pragma unroll
      for (int ni = 0; ni < NH; ++ni)
        #pragma unroll
        for (int kk = 0; kk < 2; ++kk)
          MFMA16(acc[mi][NH + ni], aa[mi][kk], bb1[ni][kk]);
    __builtin_amdgcn_s_setprio(0);
    __builtin_amdgcn_s_barrier();

    #pragma unroll
    for (int mi = 0; mi < 4; ++mi)
      #pragma unroll
      for (int kk = 0; kk < 2; ++kk)
        aa[mi][kk] = *(const s16x8*)(hA + ((mi + 4) * 16 + l15) * 128 + (((kk * 4 + l4) ^ sx) << 4));
    if (pre){ stageB(d, 0, k0n); stageB(d, 1, k0n); }
    __builtin_amdgcn_s_setprio(1);
    #pragma unroll
    for (int mi = 0; mi < 4; ++mi)
      #pragma unroll
      for (int ni = 0; ni < NH; ++ni)
        #pragma unroll
        for (int kk = 0; kk < 2; ++kk)
          MFMA16(acc[mi + 4][ni], aa[mi][kk], bb0[ni][kk]);
    __builtin_amdgcn_s_setprio(0);
    __builtin_amdgcn_s_barrier();

    if (pre){ stageA(d, 0, k0n); stageA(d, 1, k0n); }
    __builtin_amdgcn_s_setprio(1);
    #pragma unroll
    for (int mi = 0; mi < 4; ++mi)
      #pragma unroll
      for (int ni = 0; ni < NH; ++ni)
        #pragma unroll
        for (int kk = 0; kk < 2; ++kk)
          MFMA16(acc[mi + 4][NH + ni], aa[mi][kk], bb1[ni][kk]);
    __builtin_amdgcn_s_setprio(0);
    if (kt + 1 < nk){
      if (pre){
        if constexpr (TOT == 8) asm volatile("s_waitcnt vmcnt(8)" ::: "memory");
        else                    asm volatile("s_waitcnt vmcnt(6)" ::: "memory");
      } else {
        asm volatile("s_waitcnt vmcnt(0)" ::: "memory");
      }
      __builtin_amdgcn_s_barrier();
    }
  }

  if constexpr (MODE == 0){
    float* fOut = (float*)smem;
    __syncthreads();
    #pragma unroll
    for (int mi = 0; mi < 8; ++mi)
      #pragma unroll
      for (int ni = 0; ni < NREP; ++ni)
        #pragma unroll
        for (int i = 0; i < 4; ++i){
          const int rl = wr * 128 + mi * 16 + l4 * 4 + i;
          const int cl = wc * (NREP * 16) + ni * 16 + l15;
          fOut[rl * 128 + (cl ^ ((rl & 7) << 2))] = acc[mi][ni][i];
        }
    __syncthreads();
    const int c0 = (tid & 31) * 4;
    const int rb = (tid >> 5) & 15;
    #pragma unroll
    for (int j = 0; j < 16; ++j){
      const int rl = rb + j * 16;
      f32x4 vv = *(const f32x4*)(fOut + rl * 128 + (c0 ^ ((rl & 7) << 2)));
      *(f32x4*)(Cv + (size_t)(m0 + rl) * N + n0 + c0) = vv;
    }
  } else {
    const int u0 = n0 >> 7;
    const int type = (u0 >= 24) ? 2 : ((u0 >= 16) ? 1 : 0);
    const int uiw = wc >> 1;
    const int half = wc & 1;
    u16* sOut = (u16*)smem;
    __syncthreads();
    float ss[32];
    if (type < 2){
      #pragma unroll
      for (int mi = 0; mi < 8; ++mi)
        #pragma unroll
        for (int i = 0; i < 4; ++i){
          float s2 = 0.f;
          #pragma unroll
          for (int ni = 0; ni < 4; ++ni){ float x = acc[mi][ni][i]; s2 += x * x; }
          ss[mi * 4 + i] = s2;
        }
      #pragma unroll
      for (int off = 1; off < 16; off <<= 1)
        #pragma unroll
        for (int r = 0; r < 32; ++r) ss[r] += __shfl_xor(ss[r], off);
      float* sums = (float*)smem;
      if (l15 == 0){
        #pragma unroll
        for (int mi = 0; mi < 8; ++mi)
          #pragma unroll
          for (int i = 0; i < 4; ++i)
            sums[(wr * 4 + wc) * 128 + mi * 16 + l4 * 4 + i] = ss[mi * 4 + i];
      }
    }
    __syncthreads();
    if (type < 2){
      const float* sums = (const float*)smem;
      #pragma unroll
      for (int mi = 0; mi < 8; ++mi)
        #pragma unroll
        for (int i = 0; i < 4; ++i){
          float tot = ss[mi * 4 + i] + sums[(wr * 4 + (wc ^ 1)) * 128 + mi * 16 + l4 * 4 + i];
          ss[mi * 4 + i] = rsqrtf(tot * (1.0f / 128.0f) + 1e-6f);
        }
      const float* wvp = (type == 0) ? qw : kw;
      float wn[4];
      #pragma unroll
      for (int ni = 0; ni < 4; ++ni) wn[ni] = wvp[half * 64 + ni * 16 + l15];
      #pragma unroll
      for (int mi = 0; mi < 8; ++mi)
        #pragma unroll
        for (int ni = 0; ni < 4; ++ni)
          #pragma unroll
          for (int i = 0; i < 4; ++i)
            acc[mi][ni][i] *= ss[mi * 4 + i] * wn[ni];
    }
    __syncthreads();
    if (type < 2){
      #pragma unroll
      for (int mi = 0; mi < 8; ++mi)
        #pragma unroll
        for (int ni = 0; ni < 4; ++ni)
          #pragma unroll
          for (int i = 0; i < 4; ++i){
            const int rl = wr * 128 + mi * 16 + l4 * 4 + i;
            const int d  = half * 64 + ni * 16 + l15;
            sOut[(uiw * 256 + rl) * 128 + (d ^ ((rl & 7) << 3))] = f2b(acc[mi][ni][i]);
          }
    } else {
      #pragma unroll
      for (int mi = 0; mi < 8; ++mi)
        #pragma unroll
        for (int ni = 0; ni < 4; ++ni){
          const int r0 = wr * 128 + mi * 16 + l4 * 4;
          const int d  = half * 64 + ni * 16 + l15;
          u16x4 pk;
          #pragma unroll
          for (int i = 0; i < 4; ++i) pk[i] = f2b(acc[mi][ni][i]);
          *(u16x4*)(sOut + (uiw * 128 + d) * 256 + (r0 ^ ((d & 15) << 4))) = pk;
        }
    }
    __syncthreads();
    const int b_  = m0 >> 11;
    const int s0_ = m0 & 2047;
    if (type < 2){
      const int uix = tid >> 8;
      const int d0  = (tid & 15) * 8;
      const int rb  = (tid >> 4) & 15;
      const int u_  = u0 + uix;
      const float sg = (d0 < 64) ? -1.f : 1.f;
      u16* outp = (type == 0)
        ? qout + ((size_t)(b_ * 16 + u_) * 2048 + s0_) * 128
        : kout + ((size_t)(b_ * 8 + (u_ - 16)) * 2048 + s0_) * 128;
      #pragma unroll
      for (int j = 0; j < 16; ++j){
        const int rl = rb + j * 16;
        const int rowi = m0 + rl;
        const int sw = (rl & 7) << 3;
        u16x8 xs = *(const u16x8*)(sOut + (uix * 256 + rl) * 128 + (d0 ^ sw));
        u16x8 xp = *(const u16x8*)(sOut + (uix * 256 + rl) * 128 + ((d0 ^ 64) ^ sw));
        const float* cp = cosT + (size_t)rowi * 128 + d0;
        const float* sp = sinT + (size_t)rowi * 128 + d0;
        float4 ca = *(const float4*)cp,  cb = *(const float4*)(cp + 4);
        float4 sa = *(const float4*)sp,  sb = *(const float4*)(sp + 4);
        float cv[8] = {ca.x, ca.y, ca.z, ca.w, cb.x, cb.y, cb.z, cb.w};
        float sv[8] = {sa.x, sa.y, sa.z, sa.w, sb.x, sb.y, sb.z, sb.w};
        u16x8 o;
        #pragma unroll
        for (int e = 0; e < 8; ++e)
          o[e] = f2b(b2f(xs[e]) * cv[e] + sg * b2f(xp[e]) * sv[e]);
        *(u16x8*)(outp + (size_t)rl * 128 + d0) = o;
      }
    } else {
      const int rc = tid & 31;
      const int dq = (tid >> 5) & 15;
      const int r0g = rc * 8;
      #pragma unroll
      for (int ui2 = 0; ui2 < 2; ++ui2){
        const int vh = u0 + ui2 - 24;
        u16* dv = vout + ((size_t)(b_ * 8 + vh) * 128) * 2048 + s0_;
        #pragma unroll
        for (int dl = 0; dl < 8; ++dl){
          const int d = dq * 8 + dl;
          const int r0s = r0g ^ ((d & 15) << 4);
          u16x8 vv = *(const u16x8*)(sOut + (ui2 * 128 + d) * 256 + r0s);
          *(u16x8*)(dv + (size_t)d * 2048 + r0g) = vv;
        }
      }
    }
  }
}

// ---------------- flash attention v4 (round-12 verbatim) + T5 setprio ----------------
__device__ __forceinline__ void stage_kv(const u16* __restrict__ Kg, const u16* __restrict__ Vt,
                                         int kt, u16* sKb, u16* sVb, int tid){
  #pragma unroll
  for (int i = 0; i < 4; ++i){
    const int off = i * 4096 + tid * 16;
    const unsigned wub = (unsigned)(i * 4096 + (tid >> 6) * 1024);
    const int key = off >> 8, ks = (off >> 4) & 15;
    __builtin_amdgcn_global_load_lds(
        (const __attribute__((address_space(1))) void*)(Kg + (size_t)(kt * 64 + key) * 128 + ((ks ^ (key & 15)) << 3)),
        (__attribute__((address_space(3))) void*)((char*)sKb + wub), 16, 0, 0);
    const int d = off >> 7, vs = (off >> 4) & 7;
    __builtin_amdgcn_global_load_lds(
        (const __attribute__((address_space(1))) void*)(Vt + (size_t)d * 2048 + kt * 64 + ((vs ^ (d & 7)) << 3)),
        (__attribute__((address_space(3))) void*)((char*)sVb + wub), 16, 0, 0);
  }
}

__global__ __launch_bounds__(256, 2) void k_attn(const u16* __restrict__ qb, const u16* __restrict__ kb,
                                                 const u16* __restrict__ vtb, u16* __restrict__ ob){
  __shared__ __align__(128) u16 sK[2][64 * 128];
  __shared__ __align__(128) u16 sV[2][128 * 64];
  const int tid = threadIdx.x, lane = tid & 63, w = tid >> 6;
  const int hi = lane >> 5, l31 = lane & 31;
  const int bid = blockIdx.x;
  const int bh = bid & 31;
  const int kvh = bh & 7, r2 = bh >> 3;
  const int b = r2 >> 1, h = kvh * 2 + (r2 & 1);
  const int slot = bid >> 5;
  const int qt = (slot < 8) ? (15 - 2 * slot) : (2 * slot - 16);
  const u16* Q  = qb  + ((size_t)(b * 16 + h)  * 2048) * 128;
  const u16* Kg = kb  + ((size_t)(b * 8 + kvh) * 2048) * 128;
  const u16* Vt = vtb + ((size_t)(b * 8 + kvh) * 128) * 2048;
  const int qrow0 = qt * 128 + w * 32;

  s16x8 qf[8];
  #pragma unroll
  for (int ds = 0; ds < 8; ++ds)
    qf[ds] = *(const s16x8*)(Q + (size_t)(qrow0 + l31) * 128 + ds * 16 + hi * 8);

  f32x16 acc[4] = {};
  float mx = -1e30f, lsum = 0.f;
  const int nkt = qt * 2 + 2;

  stage_kv(Kg, Vt, 0, sK[0], sV[0], tid);
  for (int kt = 0; kt < nkt; ++kt){
    const int cur = kt & 1;
    if (kt + 1 < nkt){
      stage_kv(Kg, Vt, kt + 1, sK[cur ^ 1], sV[cur ^ 1], tid);
      asm volatile("s_waitcnt vmcnt(8)");
    } else {
      asm volatile("s_waitcnt vmcnt(0)");
    }
    __builtin_amdgcn_s_barrier();

    if (kt * 64 <= qrow0 + 31){
      const char* sKc = (const char*)sK[cur];
      const char* sVc = (const char*)sV[cur];
      f32x16 s0 = {}, s1 = {};
      __builtin_amdgcn_s_setprio(1);
      #pragma unroll
      for (int ds = 0; ds < 8; ++ds){
        const int sl = ((ds * 2 + hi) ^ (l31 & 15)) << 4;
        s16x8 k0 = *(const s16x8*)(sKc + l31 * 256 + sl);
        s16x8 k1 = *(const s16x8*)(sKc + 8192 + l31 * 256 + sl);
        MFMA32(s0, k0, qf[ds]);
        MFMA32(s1, k1, qf[ds]);
      }
      __builtin_amdgcn_s_setprio(0);
      const int qg = qrow0 + l31;
      const bool domask = (kt * 64 + 63) > qrow0;
      float pv0[16], pv1[16];
      float pmax = -1e30f;
      #pragma unroll
      for (int r = 0; r < 16; ++r){
        const int krow = (r & 3) + 8 * (r >> 2) + 4 * hi;
        float v0 = s0[r] * 0.08838834764831845f;
        float v1 = s1[r] * 0.08838834764831845f;
        if (domask){
          if (kt * 64 + krow > qg)      v0 = -1e30f;
          if (kt * 64 + 32 + krow > qg) v1 = -1e30f;
        }
        pv0[r] = v0; pv1[r] = v1;
        pmax = fmaxf(pmax, fmaxf(v0, v1));
      }
      pmax = fmaxf(pmax, __shfl_xor(pmax, 32));
      if (!__all(pmax - mx <= 8.f)){
        const float mn = fmaxf(mx, pmax);
        const float al = __expf(mx - mn);
        mx = mn; lsum *= al;
        #pragma unroll
        for (int r = 0; r < 16; ++r){
          const float ar = __shfl(al, (r & 3) + 8 * (r >> 2) + 4 * hi);
          acc[0][r] *= ar; acc[1][r] *= ar; acc[2][r] *= ar; acc[3][r] *= ar;
        }
      }
      float rs = 0.f;
      #pragma unroll
      for (int r = 0; r < 16; ++r){
        const float e0 = __expf(pv0[r] - mx);
        const float e1 = __expf(pv1[r] - mx);
        pv0[r] = e0; pv1[r] = e1;
        rs += e0 + e1;
      }
      rs += __shfl_xor(rs, 32);
      lsum += rs;
      #pragma unroll
      for (int s = 0; s < 4; ++s){
        const int t8 = (s & 1) * 8;
        unsigned w0, w1, w2, w3;
        if (s < 2){
          asm("v_cvt_pk_bf16_f32 %0, %1, %2" : "=v"(w0) : "v"(pv0[t8+0]), "v"(pv0[t8+1]));
          asm("v_cvt_pk_bf16_f32 %0, %1, %2" : "=v"(w1) : "v"(pv0[t8+2]), "v"(pv0[t8+3]));
          asm("v_cvt_pk_bf16_f32 %0, %1, %2" : "=v"(w2) : "v"(pv0[t8+4]), "v"(pv0[t8+5]));
          asm("v_cvt_pk_bf16_f32 %0, %1, %2" : "=v"(w3) : "v"(pv0[t8+6]), "v"(pv0[t8+7]));
        } else {
          asm("v_cvt_pk_bf16_f32 %0, %1, %2" : "=v"(w0) : "v"(pv1[t8+0]), "v"(pv1[t8+1]));
          asm("v_cvt_pk_bf16_f32 %0, %1, %2" : "=v"(w1) : "v"(pv1[t8+2]), "v"(pv1[t8+3]));
          asm("v_cvt_pk_bf16_f32 %0, %1, %2" : "=v"(w2) : "v"(pv1[t8+4]), "v"(pv1[t8+5]));
          asm("v_cvt_pk_bf16_f32 %0, %1, %2" : "=v"(w3) : "v"(pv1[t8+6]), "v"(pv1[t8+7]));
        }
        asm("v_permlane32_swap_b32 %0, %1" : "+v"(w0), "+v"(w2));
        asm("v_permlane32_swap_b32 %0, %1" : "+v"(w1), "+v"(w3));
        u32x4 pw = {w0, w1, w2, w3};
        s16x8 pa = __builtin_bit_cast(s16x8, pw);
        __builtin_amdgcn_s_setprio(1);
        #pragma unroll
        for (int db = 0; db < 4; ++db){
          const int d = db * 32 + l31;
          s16x8 vf = *(const s16x8*)(sVc + d * 128 + (((s * 2 + hi) ^ (d & 7)) << 4));
          MFMA32(acc[db], pa, vf);
        }
        __builtin_amdgcn_s_setprio(0);
      }
    }
    asm volatile("s_waitcnt lgkmcnt(0)");
    __builtin_amdgcn_s_barrier();
  }
  float li[16];
  #pragma unroll
  for (int r = 0; r < 16; ++r)
    li[r] = __shfl(lsum, (r & 3) + 8 * (r >> 2) + 4 * hi);
  #pragma unroll
  for (int db = 0; db < 4; ++db)
    #pragma unroll
    for (int r = 0; r < 16; ++r){
      const int row = qrow0 + (r & 3) + 8 * (r >> 2) + 4 * hi;
      const int col = h * 128 + db * 32 + l31;
      ob[((size_t)(b * 2048) + row) * 2048 + col] = f2b(acc[db][r] / li[r]);
    }
}

extern "C" void kernel_launch(void* const* d_in, const int* in_sizes, int n_in,
                              void* d_out, int out_size, void* d_ws, size_t ws_size,
                              hipStream_t stream){
  const float* hs   = (const float*)d_in[0];
  const float* cosT = (const float*)d_in[1];
  const float* sinT = (const float*)d_in[2];
  const float* Wq = (const float*)d_in[4];
  const float* Wk = (const float*)d_in[5];
  const float* Wv = (const float*)d_in[6];
  const float* Wo = (const float*)d_in[7];
  const float* qw = (const float*)d_in[8];
  const float* kw = (const float*)d_in[9];
  float* out = (float*)d_out;
  char* ws = (char*)d_ws;

  u16* hsb   = (u16*)(ws);                       // 16 MB  hs bf16
  u16* wqkvT = (u16*)(ws + ((size_t)16 << 20));  // 16 MB
  u16* woT   = (u16*)(ws + ((size_t)32 << 20));  //  8 MB
  u16* qb    = (u16*)(ws + ((size_t)40 << 20));  // 16 MB
  u16* kb2   = (u16*)(ws + ((size_t)56 << 20));  //  8 MB
  u16* vtb   = (u16*)(ws + ((size_t)64 << 20));  //  8 MB (transposed [bh][d][s])
  u16* attnb = (u16*)(ws + ((size_t)72 << 20));  // 16 MB

  k_cast<<<4096, 256, 0, stream>>>(hs, hsb, 1048576);
  k_transall<<<dim3(64, 256), 256, 0, stream>>>(Wq, Wk, Wv, Wo, wqkvT, woT);
  k_gemm8<4, 1><<<dim3(16, 16), 512, 0, stream>>>(hsb, wqkvT, nullptr, 4096, 4096, 2048,
                                                  qb, kb2, vtb, cosT, sinT, qw, kw);
  k_attn<<<512, 256, 0, stream>>>(qb, kb2, vtb, attnb);
  k_gemm8<2, 0><<<dim3(16, 16), 512, 0, stream>>>(attnb, woT, (float*)out, 4096, 2048, 2048,
                                                  nullptr, nullptr, nullptr, nullptr, nullptr, nullptr, nullptr);
}

// Round 15
// 206.059 us; speedup vs baseline: 1.0107x; 1.0107x over previous
//
#include <hip/hip_runtime.h>

typedef unsigned short u16;
typedef unsigned short u16x8 __attribute__((ext_vector_type(8)));
typedef unsigned short u16x4 __attribute__((ext_vector_type(4)));
typedef short s16x8 __attribute__((ext_vector_type(8)));
typedef float f32x4 __attribute__((ext_vector_type(4)));
typedef float f32x16 __attribute__((ext_vector_type(16)));
typedef unsigned u32x4 __attribute__((ext_vector_type(4)));

__device__ __forceinline__ u16 f2b(float f){
  unsigned u = __builtin_bit_cast(unsigned, f);
  u += 0x7fffu + ((u >> 16) & 1u);
  return (u16)(u >> 16);
}
__device__ __forceinline__ float b2f(u16 v){
  unsigned u = ((unsigned)v) << 16;
  return __builtin_bit_cast(float, u);
}

#define MFMA16(c, a, b) (c) = __builtin_amdgcn_mfma_f32_16x16x32_bf16((a), (b), (c), 0, 0, 0)
#define MFMA32(c, a, b) (c) = __builtin_amdgcn_mfma_f32_32x32x16_bf16((a), (b), (c), 0, 0, 0)

__device__ __forceinline__ void gl16(const u16* g, char* l){
  __builtin_amdgcn_global_load_lds((const __attribute__((address_space(1))) void*)g,
                                   (__attribute__((address_space(3))) void*)l, 16, 0, 0);
}

// ---------------- cast hidden_states f32 -> bf16 ----------------
__global__ void k_cast(const float* __restrict__ src, u16* __restrict__ dst, int n8){
  int i = blockIdx.x * blockDim.x + threadIdx.x;
  if (i >= n8) return;
  const float4* s = (const float4*)(src + (size_t)i * 8);
  float4 a = s[0], b = s[1];
  u16x8 o;
  o[0]=f2b(a.x); o[1]=f2b(a.y); o[2]=f2b(a.z); o[3]=f2b(a.w);
  o[4]=f2b(b.x); o[5]=f2b(b.y); o[6]=f2b(b.z); o[7]=f2b(b.w);
  *(u16x8*)(dst + (size_t)i * 8) = o;
}

// ------- all 4 weight transposes in ONE launch (region-decoded) -------
__global__ void k_transall(const float* __restrict__ Wq, const float* __restrict__ Wk,
                           const float* __restrict__ Wv, const float* __restrict__ Wo,
                           u16* __restrict__ wqkvT, u16* __restrict__ woT){
  __shared__ float t[32][33];
  int by = blockIdx.y;
  const float* src; u16* dst; int N;
  if (by < 64)       { src = Wq; dst = wqkvT;                        N = 2048; }
  else if (by < 128) { src = Wk; dst = wqkvT + (size_t)2048 * 2048;  N = 1024; by -= 64; }
  else if (by < 192) { src = Wv; dst = wqkvT + (size_t)3072 * 2048;  N = 1024; by -= 128; }
  else               { src = Wo; dst = woT;                          N = 2048; by -= 192; }
  int n0 = blockIdx.x * 32, k0 = by * 32;
  if (n0 >= N) return;
  int c = threadIdx.x & 31, r4 = threadIdx.x >> 5;
  #pragma unroll
  for (int p = 0; p < 4; ++p){
    int r = r4 + p * 8;
    t[r][c] = src[(size_t)(k0 + r) * N + n0 + c];
  }
  __syncthreads();
  #pragma unroll
  for (int p = 0; p < 4; ++p){
    int r = r4 + p * 8;
    dst[(size_t)(n0 + r) * 2048 + k0 + c] = f2b(t[c][r]);
  }
}

// ---------------- 8-phase GEMM: C = A(MxK) * BT(NxK)^T ----------------
template<int NREP, int MODE>
__global__ __launch_bounds__(512, 1) void k_gemm8(const u16* __restrict__ A, const u16* __restrict__ BT,
                                                  float* __restrict__ Cv, int M, int N, int K,
                                                  u16* __restrict__ qout, u16* __restrict__ kout,
                                                  u16* __restrict__ vout,
                                                  const float* __restrict__ cosT, const float* __restrict__ sinT,
                                                  const float* __restrict__ qw, const float* __restrict__ kw){
  constexpr int NH = NREP / 2;
  constexpr int BROWS = NREP * 32;
  constexpr int BLOADS = NREP / 2;
  constexpr int TOT = 4 + 2 * BLOADS;
  constexpr int SMEM0 = 65536 + 2 * 2 * BROWS * 64 * 2;
  constexpr int SMEM = (SMEM0 > 131072) ? SMEM0 : 131072;
  __shared__ __align__(128) char smem[SMEM];
  u16* sAp = (u16*)smem;
  u16* sBp = (u16*)(smem + 65536);
  const int tid = threadIdx.x;
  const int lane = tid & 63, w = tid >> 6;
  const int l15 = lane & 15, l4 = lane >> 4;
  const int sx = l15 & 7;
  const int wr = w >> 2, wc = w & 3;
  const int m0 = blockIdx.y * 256, n0 = blockIdx.x * (NREP * 64);
  const int nk = K >> 6;

  f32x4 acc[8][NREP];
  #pragma unroll
  for (int mi = 0; mi < 8; ++mi)
    #pragma unroll
    for (int ni = 0; ni < NREP; ++ni) acc[mi][ni] = (f32x4){0.f, 0.f, 0.f, 0.f};

  auto stageA = [&](int d, int half, int k0){
    #pragma unroll
    for (int j = 0; j < 2; ++j){
      const int q = j * 512 + tid;
      const int r = q >> 3, cc = q & 7;
      gl16(A + (size_t)(m0 + half * 128 + r) * K + k0 + ((cc ^ (r & 7)) << 3),
           (char*)(sAp + (d * 2 + half) * 8192) + j * 8192 + (tid >> 6) * 1024);
    }
  };
  auto stageB = [&](int d, int half, int k0){
    #pragma unroll
    for (int j = 0; j < BLOADS; ++j){
      const int q = j * 512 + tid;
      const int r = q >> 3, cc = q & 7;
      gl16(BT + (size_t)(n0 + half * BROWS + r) * K + k0 + ((cc ^ (r & 7)) << 3),
           (char*)(sBp + (d * 2 + half) * (BROWS * 64)) + j * 8192 + (tid >> 6) * 1024);
    }
  };

  stageA(0, 0, 0); stageA(0, 1, 0); stageB(0, 0, 0); stageB(0, 1, 0);
  stageA(1, 0, 64); stageA(1, 1, 64); stageB(1, 0, 64); stageB(1, 1, 64);
  if constexpr (TOT == 8) asm volatile("s_waitcnt vmcnt(8)" ::: "memory");
  else                    asm volatile("s_waitcnt vmcnt(6)" ::: "memory");
  __builtin_amdgcn_s_barrier();

  const int halfB = wc >> 1;
  const int rb0 = (wc & 1) * (NREP * 16);

  for (int kt = 0; kt < nk; ++kt){
    const int d = kt & 1;
    const bool pre = (kt + 2) < nk;
    const int k0n = (kt + 2) << 6;
    const char* hA = (const char*)(sAp + (d * 2 + wr) * 8192);
    const char* hB = (const char*)(sBp + (d * 2 + halfB) * (BROWS * 64));
    s16x8 aa[4][2], bb0[NH][2], bb1[NH][2];

    #pragma unroll
    for (int mi = 0; mi < 4; ++mi)
      #pragma unroll
      for (int kk = 0; kk < 2; ++kk)
        aa[mi][kk] = *(const s16x8*)(hA + (mi * 16 + l15) * 128 + (((kk * 4 + l4) ^ sx) << 4));
    #pragma unroll
    for (int ni = 0; ni < NH; ++ni)
      #pragma unroll
      for (int kk = 0; kk < 2; ++kk)
        bb0[ni][kk] = *(const s16x8*)(hB + (rb0 + ni * 16 + l15) * 128 + (((kk * 4 + l4) ^ sx) << 4));
    __builtin_amdgcn_s_setprio(1);
    #pragma unroll
    for (int mi = 0; mi < 4; ++mi)
      #pragma unroll
      for (int ni = 0; ni < NH; ++ni)
        #pragma unroll
        for (int kk = 0; kk < 2; ++kk)
          MFMA16(acc[mi][ni], aa[mi][kk], bb0[ni][kk]);
    __builtin_amdgcn_s_setprio(0);

    #pragma unroll
    for (int ni = 0; ni < NH; ++ni)
      #pragma unroll
      for (int kk = 0; kk < 2; ++kk)
        bb1[ni][kk] = *(const s16x8*)(hB + (rb0 + (NH + ni) * 16 + l15) * 128 + (((kk * 4 + l4) ^ sx) << 4));
    __builtin_amdgcn_s_setprio(1);
    #pragma unroll
    for (int mi = 0; mi < 4; ++mi)
      #pragma unroll
      for (int ni = 0; ni < NH; ++ni)
        #pragma unroll
        for (int kk = 0; kk < 2; ++kk)
          MFMA16(acc[mi][NH + ni], aa[mi][kk], bb1[ni][kk]);
    __builtin_amdgcn_s_setprio(0);
    __builtin_amdgcn_s_barrier();

    #pragma unroll
    for (int mi = 0; mi < 4; ++mi)
      #pragma unroll
      for (int kk = 0; kk < 2; ++kk)
        aa[mi][kk] = *(const s16x8*)(hA + ((mi + 4) * 16 + l15) * 128 + (((kk * 4 + l4) ^ sx) << 4));
    if (pre){ stageB(d, 0, k0n); stageB(d, 1, k0n); }
    __builtin_amdgcn_s_setprio(1);
    #pragma unroll
    for (int mi = 0; mi < 4; ++mi)
      #pragma unroll
      for (int ni = 0; ni < NH; ++ni)
        #pragma unroll
        for (int kk = 0; kk < 2; ++kk)
          MFMA16(acc[mi + 4][ni], aa[mi][kk], bb0[ni][kk]);
    __builtin_amdgcn_s_setprio(0);
    __builtin_amdgcn_s_barrier();

    if (pre){ stageA(d, 0, k0n); stageA(d, 1, k0n); }
    __builtin_amdgcn_s_setprio(1);
    #pragma unroll
    for (int mi = 0; mi < 4; ++mi)
      #pragma unroll
      for (int ni = 0; ni < NH; ++ni)
        #pragma unroll
        for (int kk = 0; kk < 2; ++kk)
          MFMA16(acc[mi + 4][NH + ni], aa[mi][kk], bb1[ni][kk]);
    __builtin_amdgcn_s_setprio(0);
    if (kt + 1 < nk){
      if (pre){
        if constexpr (TOT == 8) asm volatile("s_waitcnt vmcnt(8)" ::: "memory");
        else                    asm volatile("s_waitcnt vmcnt(6)" ::: "memory");
      } else {
        asm volatile("s_waitcnt vmcnt(0)" ::: "memory");
      }
      __builtin_amdgcn_s_barrier();
    }
  }

  if constexpr (MODE == 0){
    float* fOut = (float*)smem;
    __syncthreads();
    #pragma unroll
    for (int mi = 0; mi < 8; ++mi)
      #pragma unroll
      for (int ni = 0; ni < NREP; ++ni)
        #pragma unroll
        for (int i = 0; i < 4; ++i){
          const int rl = wr * 128 + mi * 16 + l4 * 4 + i;
          const int cl = wc * (NREP * 16) + ni * 16 + l15;
          fOut[rl * 128 + (cl ^ ((rl & 7) << 2))] = acc[mi][ni][i];
        }
    __syncthreads();
    const int c0 = (tid & 31) * 4;
    const int rb = (tid >> 5) & 15;
    #pragma unroll
    for (int j = 0; j < 16; ++j){
      const int rl = rb + j * 16;
      f32x4 vv = *(const f32x4*)(fOut + rl * 128 + (c0 ^ ((rl & 7) << 2)));
      *(f32x4*)(Cv + (size_t)(m0 + rl) * N + n0 + c0) = vv;
    }
  } else {
    const int u0 = n0 >> 7;
    const int type = (u0 >= 24) ? 2 : ((u0 >= 16) ? 1 : 0);
    const int uiw = wc >> 1;
    const int half = wc & 1;
    u16* sOut = (u16*)smem;
    __syncthreads();
    float ss[32];
    if (type < 2){
      #pragma unroll
      for (int mi = 0; mi < 8; ++mi)
        #pragma unroll
        for (int i = 0; i < 4; ++i){
          float s2 = 0.f;
          #pragma unroll
          for (int ni = 0; ni < 4; ++ni){ float x = acc[mi][ni][i]; s2 += x * x; }
          ss[mi * 4 + i] = s2;
        }
      #pragma unroll
      for (int off = 1; off < 16; off <<= 1)
        #pragma unroll
        for (int r = 0; r < 32; ++r) ss[r] += __shfl_xor(ss[r], off);
      float* sums = (float*)smem;
      if (l15 == 0){
        #pragma unroll
        for (int mi = 0; mi < 8; ++mi)
          #pragma unroll
          for (int i = 0; i < 4; ++i)
            sums[(wr * 4 + wc) * 128 + mi * 16 + l4 * 4 + i] = ss[mi * 4 + i];
      }
    }
    __syncthreads();
    if (type < 2){
      const float* sums = (const float*)smem;
      #pragma unroll
      for (int mi = 0; mi < 8; ++mi)
        #pragma unroll
        for (int i = 0; i < 4; ++i){
          float tot = ss[mi * 4 + i] + sums[(wr * 4 + (wc ^ 1)) * 128 + mi * 16 + l4 * 4 + i];
          ss[mi * 4 + i] = rsqrtf(tot * (1.0f / 128.0f) + 1e-6f);
        }
      const float* wvp = (type == 0) ? qw : kw;
      float wn[4];
      #pragma unroll
      for (int ni = 0; ni < 4; ++ni) wn[ni] = wvp[half * 64 + ni * 16 + l15];
      #pragma unroll
      for (int mi = 0; mi < 8; ++mi)
        #pragma unroll
        for (int ni = 0; ni < 4; ++ni)
          #pragma unroll
          for (int i = 0; i < 4; ++i)
            acc[mi][ni][i] *= ss[mi * 4 + i] * wn[ni];
    }
    __syncthreads();
    if (type < 2){
      #pragma unroll
      for (int mi = 0; mi < 8; ++mi)
        #pragma unroll
        for (int ni = 0; ni < 4; ++ni)
          #pragma unroll
          for (int i = 0; i < 4; ++i){
            const int rl = wr * 128 + mi * 16 + l4 * 4 + i;
            const int d  = half * 64 + ni * 16 + l15;
            sOut[(uiw * 256 + rl) * 128 + (d ^ ((rl & 7) << 3))] = f2b(acc[mi][ni][i]);
          }
    } else {
      #pragma unroll
      for (int mi = 0; mi < 8; ++mi)
        #pragma unroll
        for (int ni = 0; ni < 4; ++ni){
          const int r0 = wr * 128 + mi * 16 + l4 * 4;
          const int d  = half * 64 + ni * 16 + l15;
          u16x4 pk;
          #pragma unroll
          for (int i = 0; i < 4; ++i) pk[i] = f2b(acc[mi][ni][i]);
          *(u16x4*)(sOut + (uiw * 128 + d) * 256 + (r0 ^ ((d & 15) << 4))) = pk;
        }
    }
    __syncthreads();
    const int b_  = m0 >> 11;
    const int s0_ = m0 & 2047;
    if (type < 2){
      const int uix = tid >> 8;
      const int d0  = (tid & 15) * 8;
      const int rb  = (tid >> 4) & 15;
      const int u_  = u0 + uix;
      const float sg = (d0 < 64) ? -1.f : 1.f;
      u16* outp = (type == 0)
        ? qout + ((size_t)(b_ * 16 + u_) * 2048 + s0_) * 128
        : kout + ((size_t)(b_ * 8 + (u_ - 16)) * 2048 + s0_) * 128;
      #pragma unroll
      for (int j = 0; j < 16; ++j){
        const int rl = rb + j * 16;
        const int rowi = m0 + rl;
        const int sw = (rl & 7) << 3;
        u16x8 xs = *(const u16x8*)(sOut + (uix * 256 + rl) * 128 + (d0 ^ sw));
        u16x8 xp = *(const u16x8*)(sOut + (uix * 256 + rl) * 128 + ((d0 ^ 64) ^ sw));
        const float* cp = cosT + (size_t)rowi * 128 + d0;
        const float* sp = sinT + (size_t)rowi * 128 + d0;
        float4 ca = *(const float4*)cp,  cb = *(const float4*)(cp + 4);
        float4 sa = *(const float4*)sp,  sb = *(const float4*)(sp + 4);
        float cv[8] = {ca.x, ca.y, ca.z, ca.w, cb.x, cb.y, cb.z, cb.w};
        float sv[8] = {sa.x, sa.y, sa.z, sa.w, sb.x, sb.y, sb.z, sb.w};
        u16x8 o;
        #pragma unroll
        for (int e = 0; e < 8; ++e)
          o[e] = f2b(b2f(xs[e]) * cv[e] + sg * b2f(xp[e]) * sv[e]);
        *(u16x8*)(outp + (size_t)rl * 128 + d0) = o;
      }
    } else {
      const int rc = tid & 31;
      const int dq = (tid >> 5) & 15;
      const int r0g = rc * 8;
      #pragma unroll
      for (int ui2 = 0; ui2 < 2; ++ui2){
        const int vh = u0 + ui2 - 24;
        u16* dv = vout + ((size_t)(b_ * 8 + vh) * 128) * 2048 + s0_;
        #pragma unroll
        for (int dl = 0; dl < 8; ++dl){
          const int d = dq * 8 + dl;
          const int r0s = r0g ^ ((d & 15) << 4);
          u16x8 vv = *(const u16x8*)(sOut + (ui2 * 128 + d) * 256 + r0s);
          *(u16x8*)(dv + (size_t)d * 2048 + r0g) = vv;
        }
      }
    }
  }
}

// ---------------- flash attention v4 (round-12 verbatim: best measured) ----------------
__device__ __forceinline__ void stage_kv(const u16* __restrict__ Kg, const u16* __restrict__ Vt,
                                         int kt, u16* sKb, u16* sVb, int tid){
  #pragma unroll
  for (int i = 0; i < 4; ++i){
    const int off = i * 4096 + tid * 16;
    const unsigned wub = (unsigned)(i * 4096 + (tid >> 6) * 1024);
    const int key = off >> 8, ks = (off >> 4) & 15;
    __builtin_amdgcn_global_load_lds(
        (const __attribute__((address_space(1))) void*)(Kg + (size_t)(kt * 64 + key) * 128 + ((ks ^ (key & 15)) << 3)),
        (__attribute__((address_space(3))) void*)((char*)sKb + wub), 16, 0, 0);
    const int d = off >> 7, vs = (off >> 4) & 7;
    __builtin_amdgcn_global_load_lds(
        (const __attribute__((address_space(1))) void*)(Vt + (size_t)d * 2048 + kt * 64 + ((vs ^ (d & 7)) << 3)),
        (__attribute__((address_space(3))) void*)((char*)sVb + wub), 16, 0, 0);
  }
}

__global__ __launch_bounds__(256, 2) void k_attn(const u16* __restrict__ qb, const u16* __restrict__ kb,
                                                 const u16* __restrict__ vtb, u16* __restrict__ ob){
  __shared__ __align__(128) u16 sK[2][64 * 128];
  __shared__ __align__(128) u16 sV[2][128 * 64];
  const int tid = threadIdx.x, lane = tid & 63, w = tid >> 6;
  const int hi = lane >> 5, l31 = lane & 31;
  const int bid = blockIdx.x;
  const int bh = bid & 31;
  const int kvh = bh & 7, r2 = bh >> 3;
  const int b = r2 >> 1, h = kvh * 2 + (r2 & 1);
  const int slot = bid >> 5;
  const int qt = (slot < 8) ? (15 - 2 * slot) : (2 * slot - 16);
  const u16* Q  = qb  + ((size_t)(b * 16 + h)  * 2048) * 128;
  const u16* Kg = kb  + ((size_t)(b * 8 + kvh) * 2048) * 128;
  const u16* Vt = vtb + ((size_t)(b * 8 + kvh) * 128) * 2048;
  const int qrow0 = qt * 128 + w * 32;

  s16x8 qf[8];
  #pragma unroll
  for (int ds = 0; ds < 8; ++ds)
    qf[ds] = *(const s16x8*)(Q + (size_t)(qrow0 + l31) * 128 + ds * 16 + hi * 8);

  f32x16 acc[4] = {};
  float mx = -1e30f, lsum = 0.f;
  const int nkt = qt * 2 + 2;

  stage_kv(Kg, Vt, 0, sK[0], sV[0], tid);
  for (int kt = 0; kt < nkt; ++kt){
    const int cur = kt & 1;
    if (kt + 1 < nkt){
      stage_kv(Kg, Vt, kt + 1, sK[cur ^ 1], sV[cur ^ 1], tid);
      asm volatile("s_waitcnt vmcnt(8)");
    } else {
      asm volatile("s_waitcnt vmcnt(0)");
    }
    __builtin_amdgcn_s_barrier();

    if (kt * 64 <= qrow0 + 31){
      const char* sKc = (const char*)sK[cur];
      const char* sVc = (const char*)sV[cur];
      f32x16 s0 = {}, s1 = {};
      #pragma unroll
      for (int ds = 0; ds < 8; ++ds){
        const int sl = ((ds * 2 + hi) ^ (l31 & 15)) << 4;
        s16x8 k0 = *(const s16x8*)(sKc + l31 * 256 + sl);
        s16x8 k1 = *(const s16x8*)(sKc + 8192 + l31 * 256 + sl);
        MFMA32(s0, k0, qf[ds]);
        MFMA32(s1, k1, qf[ds]);
      }
      const int qg = qrow0 + l31;
      const bool domask = (kt * 64 + 63) > qrow0;
      float pv0[16], pv1[16];
      float pmax = -1e30f;
      #pragma unroll
      for (int r = 0; r < 16; ++r){
        const int krow = (r & 3) + 8 * (r >> 2) + 4 * hi;
        float v0 = s0[r] * 0.08838834764831845f;
        float v1 = s1[r] * 0.08838834764831845f;
        if (domask){
          if (kt * 64 + krow > qg)      v0 = -1e30f;
          if (kt * 64 + 32 + krow > qg) v1 = -1e30f;
        }
        pv0[r] = v0; pv1[r] = v1;
        pmax = fmaxf(pmax, fmaxf(v0, v1));
      }
      pmax = fmaxf(pmax, __shfl_xor(pmax, 32));
      if (!__all(pmax - mx <= 8.f)){
        const float mn = fmaxf(mx, pmax);
        const float al = __expf(mx - mn);
        mx = mn; lsum *= al;
        #pragma unroll
        for (int r = 0; r < 16; ++r){
          const float ar = __shfl(al, (r & 3) + 8 * (r >> 2) + 4 * hi);
          acc[0][r] *= ar; acc[1][r] *= ar; acc[2][r] *= ar; acc[3][r] *= ar;
        }
      }
      float rs = 0.f;
      #pragma unroll
      for (int r = 0; r < 16; ++r){
        const float e0 = __expf(pv0[r] - mx);
        const float e1 = __expf(pv1[r] - mx);
        pv0[r] = e0; pv1[r] = e1;
        rs += e0 + e1;
      }
      rs += __shfl_xor(rs, 32);
      lsum += rs;
      #pragma unroll
      for (int s = 0; s < 4; ++s){
        const int t8 = (s & 1) * 8;
        unsigned w0, w1, w2, w3;
        if (s < 2){
          asm("v_cvt_pk_bf16_f32 %0, %1, %2" : "=v"(w0) : "v"(pv0[t8+0]), "v"(pv0[t8+1]));
          asm("v_cvt_pk_bf16_f32 %0, %1, %2" : "=v"(w1) : "v"(pv0[t8+2]), "v"(pv0[t8+3]));
          asm("v_cvt_pk_bf16_f32 %0, %1, %2" : "=v"(w2) : "v"(pv0[t8+4]), "v"(pv0[t8+5]));
          asm("v_cvt_pk_bf16_f32 %0, %1, %2" : "=v"(w3) : "v"(pv0[t8+6]), "v"(pv0[t8+7]));
        } else {
          asm("v_cvt_pk_bf16_f32 %0, %1, %2" : "=v"(w0) : "v"(pv1[t8+0]), "v"(pv1[t8+1]));
          asm("v_cvt_pk_bf16_f32 %0, %1, %2" : "=v"(w1) : "v"(pv1[t8+2]), "v"(pv1[t8+3]));
          asm("v_cvt_pk_bf16_f32 %0, %1, %2" : "=v"(w2) : "v"(pv1[t8+4]), "v"(pv1[t8+5]));
          asm("v_cvt_pk_bf16_f32 %0, %1, %2" : "=v"(w3) : "v"(pv1[t8+6]), "v"(pv1[t8+7]));
        }
        asm("v_permlane32_swap_b32 %0, %1" : "+v"(w0), "+v"(w2));
        asm("v_permlane32_swap_b32 %0, %1" : "+v"(w1), "+v"(w3));
        u32x4 pw = {w0, w1, w2, w3};
        s16x8 pa = __builtin_bit_cast(s16x8, pw);
        #pragma unroll
        for (int db = 0; db < 4; ++db){
          const int d = db * 32 + l31;
          s16x8 vf = *(const s16x8*)(sVc + d * 128 + (((s * 2 + hi) ^ (d & 7)) << 4));
          MFMA32(acc[db], pa, vf);
        }
      }
    }
    asm volatile("s_waitcnt lgkmcnt(0)");
    __builtin_amdgcn_s_barrier();
  }
  float li[16];
  #pragma unroll
  for (int r = 0; r < 16; ++r)
    li[r] = __shfl(lsum, (r & 3) + 8 * (r >> 2) + 4 * hi);
  #pragma unroll
  for (int db = 0; db < 4; ++db)
    #pragma unroll
    for (int r = 0; r < 16; ++r){
      const int row = qrow0 + (r & 3) + 8 * (r >> 2) + 4 * hi;
      const int col = h * 128 + db * 32 + l31;
      ob[((size_t)(b * 2048) + row) * 2048 + col] = f2b(acc[db][r] / li[r]);
    }
}

extern "C" void kernel_launch(void* const* d_in, const int* in_sizes, int n_in,
                              void* d_out, int out_size, void* d_ws, size_t ws_size,
                              hipStream_t stream){
  const float* hs   = (const float*)d_in[0];
  const float* cosT = (const float*)d_in[1];
  const float* sinT = (const float*)d_in[2];
  const float* Wq = (const float*)d_in[4];
  const float* Wk = (const float*)d_in[5];
  const float* Wv = (const float*)d_in[6];
  const float* Wo = (const float*)d_in[7];
  const float* qw = (const float*)d_in[8];
  const float* kw = (const float*)d_in[9];
  float* out = (float*)d_out;
  char* ws = (char*)d_ws;

  u16* hsb   = (u16*)(ws);                       // 16 MB  hs bf16
  u16* wqkvT = (u16*)(ws + ((size_t)16 << 20));  // 16 MB
  u16* woT   = (u16*)(ws + ((size_t)32 << 20));  //  8 MB
  u16* qb    = (u16*)(ws + ((size_t)40 << 20));  // 16 MB
  u16* kb2   = (u16*)(ws + ((size_t)56 << 20));  //  8 MB
  u16* vtb   = (u16*)(ws + ((size_t)64 << 20));  //  8 MB (transposed [bh][d][s])
  u16* attnb = (u16*)(ws + ((size_t)72 << 20));  // 16 MB

  k_cast<<<4096, 256, 0, stream>>>(hs, hsb, 1048576);
  k_transall<<<dim3(64, 256), 256, 0, stream>>>(Wq, Wk, Wv, Wo, wqkvT, woT);
  k_gemm8<4, 1><<<dim3(16, 16), 512, 0, stream>>>(hsb, wqkvT, nullptr, 4096, 4096, 2048,
                                                  qb, kb2, vtb, cosT, sinT, qw, kw);
  k_attn<<<512, 256, 0, stream>>>(qb, kb2, vtb, attnb);
  k_gemm8<2, 0><<<dim3(16, 16), 512, 0, stream>>>(attnb, woT, (float*)out, 4096, 2048, 2048,
                                                  nullptr, nullptr, nullptr, nullptr, nullptr, nullptr, nullptr);
}